// Round 1
// baseline (7038.522 us; speedup 1.0000x reference)
//
#include <hip/hip_runtime.h>

// Kalman filter forward: out[b,v,t] for t>=1 is y_t = H m_t with
//   m_{t+1} = M_t m_t + G_t x[:, :, t],  M_t = F(I - K_t H), G_t = F K_t.
// KEY: P0 = I for all batches and the Riccati recursion is data-independent,
// so K_t (hence M_t, G_t) is IDENTICAL across the 128 batches. Phase 1
// computes the K/M/G sequence once (1 block, sequential in t); phase 2 runs
// the cheap per-batch linear recursion (128 blocks).

#define SD 64
#define NV 32
#define TSZ 128
#define BSZ 128
#define NSTEP (TSZ - 1)

// ws layout (floats)
#define MG_STRIDE (SD*SD + SD*NV)          // 6144 per step: M then G
#define WS_FT  (NSTEP * MG_STRIDE)         // F^T, 4096 floats
#define WS_HT  (WS_FT + SD*SD)             // H^T, 2048 floats

// C[i0..i0+RI-1][j0..j0+3] += A[MxKK] @ B[KKxN]; A,B row-major with given LD.
template<int RI, int KK, int LDA, int LDB>
__device__ __forceinline__ void mm_acc(float acc[RI][4],
                                       const float* __restrict__ A, int i0,
                                       const float* __restrict__ B, int j0) {
  for (int k4 = 0; k4 < KK; k4 += 4) {
    float4 b0 = *(const float4*)(B + (k4+0)*LDB + j0);
    float4 b1 = *(const float4*)(B + (k4+1)*LDB + j0);
    float4 b2 = *(const float4*)(B + (k4+2)*LDB + j0);
    float4 b3 = *(const float4*)(B + (k4+3)*LDB + j0);
#pragma unroll
    for (int r = 0; r < RI; ++r) {
      float4 a = *(const float4*)(A + (i0+r)*LDA + k4);
      acc[r][0] += a.x*b0.x + a.y*b1.x + a.z*b2.x + a.w*b3.x;
      acc[r][1] += a.x*b0.y + a.y*b1.y + a.z*b2.y + a.w*b3.y;
      acc[r][2] += a.x*b0.z + a.y*b1.z + a.z*b2.z + a.w*b3.z;
      acc[r][3] += a.x*b0.w + a.y*b1.w + a.z*b2.w + a.w*b3.w;
    }
  }
}

__launch_bounds__(256)
__global__ void kf_phase1(const float* __restrict__ Fg,
                          const float* __restrict__ Hg,
                          const float* __restrict__ Rg,
                          const float* __restrict__ Qg,
                          float* __restrict__ ws) {
  __shared__ __align__(16) float Pm[SD*SD];   // P (persistent across steps)
  __shared__ __align__(16) float Zb[SD*SD];   // scratch: Saug ping/pong, HP, Z
  __shared__ __align__(16) float PH[SD*NV];   // P H^T, later F K
  __shared__ __align__(16) float Kb[SD*NV];   // K
  __shared__ __align__(16) float Hs[NV*SD];   // H staged
  const int tid = threadIdx.x;

  // Stage H; build F^T and H^T in ws; P = I.
  for (int s = tid; s < NV*SD; s += 256) Hs[s] = Hg[s];
  for (int s = tid; s < SD*SD; s += 256) {
    int k = s >> 6, i = s & 63;
    ws[WS_FT + s] = Fg[i*SD + k];
  }
  for (int s = tid; s < SD*NV; s += 256) {
    int k = s >> 5, v = s & 31;
    ws[WS_HT + s] = Hg[v*SD + k];
  }
  for (int s = tid; s < SD*SD; s += 256)
    Pm[s] = ((s >> 6) == (s & 63)) ? 1.0f : 0.0f;
  __syncthreads();

  const float* Ftg = ws + WS_FT;
  const float* Htg = ws + WS_HT;
  float* Sa = Zb;           // 32x64 augmented [S | I]
  float* Sb = Zb + 2048;    // ping-pong buffer

  for (int t = 0; t < NSTEP; ++t) {
    float* Mws = ws + (size_t)t * MG_STRIDE;
    float* Gws = Mws + SD*SD;

    // 1: PH = P @ H^T   (64x32, K=64)
    {
      const int i0 = (tid >> 3) * 2, j0 = (tid & 7) * 4;
      float acc[2][4] = {};
      mm_acc<2,64,64,32>(acc, Pm, i0, Htg, j0);
#pragma unroll
      for (int r = 0; r < 2; ++r)
        *(float4*)(PH + (i0+r)*NV + j0) =
            make_float4(acc[r][0], acc[r][1], acc[r][2], acc[r][3]);
    }
    __syncthreads();

    // 2: Sa = [H @ PH + R | I]   (32 rows, stride 64)
    {
      const int i0 = tid >> 3, j0 = (tid & 7) * 4;
      float acc[1][4];
      float4 rr = *(const float4*)(Rg + i0*NV + j0);
      acc[0][0] = rr.x; acc[0][1] = rr.y; acc[0][2] = rr.z; acc[0][3] = rr.w;
      mm_acc<1,64,64,32>(acc, Hs, i0, PH, j0);
      *(float4*)(Sa + i0*64 + j0) =
          make_float4(acc[0][0], acc[0][1], acc[0][2], acc[0][3]);
      float4 id;
      id.x = (i0 == j0+0) ? 1.f : 0.f;
      id.y = (i0 == j0+1) ? 1.f : 0.f;
      id.z = (i0 == j0+2) ? 1.f : 0.f;
      id.w = (i0 == j0+3) ? 1.f : 0.f;
      *(float4*)(Sa + i0*64 + 32 + j0) = id;
    }
    __syncthreads();

    // 3: Gauss-Jordan inverse of S (SPD, no pivoting), ping-pong, 32 iters.
    {
      const int r = tid >> 3, c0 = (tid & 7) * 8;
      for (int p = 0; p < 32; ++p) {
        const float* X = (p & 1) ? Sb : Sa;
        float*       Y = (p & 1) ? Sa : Sb;
        const float invp = 1.0f / X[p*64 + p];
        if (r == p) {
#pragma unroll
          for (int c = 0; c < 8; ++c) Y[r*64 + c0 + c] = X[p*64 + c0 + c] * invp;
        } else {
          const float f = X[r*64 + p] * invp;
#pragma unroll
          for (int c = 0; c < 8; ++c)
            Y[r*64 + c0 + c] = X[r*64 + c0 + c] - f * X[p*64 + c0 + c];
        }
        __syncthreads();
      }
      // result (after even # of iters) back in Sa; Sinv = Sa cols [32:64)
    }

    // 4: K = PH @ Sinv   (64x32, K=32)
    {
      const int i0 = (tid >> 3) * 2, j0 = (tid & 7) * 4;
      float acc[2][4] = {};
      mm_acc<2,32,32,64>(acc, PH, i0, Sa + 32, j0);
#pragma unroll
      for (int r = 0; r < 2; ++r)
        *(float4*)(Kb + (i0+r)*NV + j0) =
            make_float4(acc[r][0], acc[r][1], acc[r][2], acc[r][3]);
    }
    __syncthreads();

    // 5: HP = H @ P  (32x64, stride 64) into Zb[0:2048] (Sinv dead now)
    {
      const int i0 = (tid >> 4) * 2, j0 = (tid & 15) * 4;
      float acc[2][4] = {};
      mm_acc<2,64,64,64>(acc, Hs, i0, Pm, j0);
#pragma unroll
      for (int r = 0; r < 2; ++r)
        *(float4*)(Zb + (i0+r)*64 + j0) =
            make_float4(acc[r][0], acc[r][1], acc[r][2], acc[r][3]);
    }
    __syncthreads();

    // 6: P_u = P - K @ HP   (in place, 64x64, K=32)
    {
      const int i0 = (tid >> 4) * 4, j0 = (tid & 15) * 4;
      float acc[4][4] = {};
      mm_acc<4,32,32,64>(acc, Kb, i0, Zb, j0);
#pragma unroll
      for (int r = 0; r < 4; ++r) {
        float4 pv = *(const float4*)(Pm + (i0+r)*64 + j0);
        pv.x -= acc[r][0]; pv.y -= acc[r][1]; pv.z -= acc[r][2]; pv.w -= acc[r][3];
        *(float4*)(Pm + (i0+r)*64 + j0) = pv;
      }
    }
    __syncthreads();

    // 7: Z = F @ P_u   (64x64, K=64) into Zb
    {
      const int i0 = (tid >> 4) * 4, j0 = (tid & 15) * 4;
      float acc[4][4] = {};
      mm_acc<4,64,64,64>(acc, Fg, i0, Pm, j0);
#pragma unroll
      for (int r = 0; r < 4; ++r)
        *(float4*)(Zb + (i0+r)*64 + j0) =
            make_float4(acc[r][0], acc[r][1], acc[r][2], acc[r][3]);
    }
    __syncthreads();

    // 8: P = Z @ F^T + Q   (64x64, K=64)
    {
      const int i0 = (tid >> 4) * 4, j0 = (tid & 15) * 4;
      float acc[4][4];
#pragma unroll
      for (int r = 0; r < 4; ++r) {
        float4 qv = *(const float4*)(Qg + (i0+r)*64 + j0);
        acc[r][0] = qv.x; acc[r][1] = qv.y; acc[r][2] = qv.z; acc[r][3] = qv.w;
      }
      mm_acc<4,64,64,64>(acc, Zb, i0, Ftg, j0);
#pragma unroll
      for (int r = 0; r < 4; ++r)
        *(float4*)(Pm + (i0+r)*64 + j0) =
            make_float4(acc[r][0], acc[r][1], acc[r][2], acc[r][3]);
    }
    __syncthreads();

    // 9: FK = F @ K  (64x32, K=64) into PH buffer, and G_t -> ws
    {
      const int i0 = (tid >> 3) * 2, j0 = (tid & 7) * 4;
      float acc[2][4] = {};
      mm_acc<2,64,64,32>(acc, Fg, i0, Kb, j0);
#pragma unroll
      for (int r = 0; r < 2; ++r) {
        float4 w = make_float4(acc[r][0], acc[r][1], acc[r][2], acc[r][3]);
        *(float4*)(PH + (i0+r)*NV + j0) = w;
        *(float4*)(Gws + (i0+r)*NV + j0) = w;
      }
    }
    __syncthreads();

    // 10: M_t = F - FK @ H  (64x64, K=32) -> ws
    {
      const int i0 = (tid >> 4) * 4, j0 = (tid & 15) * 4;
      float acc[4][4] = {};
      mm_acc<4,32,32,64>(acc, PH, i0, Hs, j0);
#pragma unroll
      for (int r = 0; r < 4; ++r) {
        float4 fv = *(const float4*)(Fg + (i0+r)*64 + j0);
        fv.x -= acc[r][0]; fv.y -= acc[r][1]; fv.z -= acc[r][2]; fv.w -= acc[r][3];
        *(float4*)(Mws + (i0+r)*64 + j0) = fv;
      }
    }
    __syncthreads();
  }
}

__launch_bounds__(256)
__global__ void kf_phase2(const float* __restrict__ x,
                          const float* __restrict__ Hg,
                          const float* __restrict__ ws,
                          float* __restrict__ out) {
  __shared__ __align__(16) float Hs[NV*SD];
  __shared__ __align__(16) float ybuf[NV*TSZ];
  __shared__ __align__(16) float msh[SD];
  __shared__ __align__(16) float mn[SD];
  __shared__ __align__(16) float ov[NV];
  const int tid = threadIdx.x;
  const int b = blockIdx.x;

  for (int s = tid; s < NV*SD; s += 256) Hs[s] = Hg[s];
  if (tid < SD) msh[tid] = 0.0f;
  if (tid < NV) ybuf[tid*TSZ] = 0.0f;    // out[:, :, 0] = 0
  __syncthreads();

  const int i  = tid >> 2, p4 = tid & 3;  // m_new: 4 threads per state row
  const int v  = tid >> 3, p8 = tid & 7;  // y: 8 threads per observed var

  for (int t = 0; t < NSTEP; ++t) {
    if (tid < NV) ov[tid] = x[(b*NV + tid)*TSZ + t];
    __syncthreads();

    const float* Mt = ws + (size_t)t * MG_STRIDE;
    const float* Gt = Mt + SD*SD;

    // m_new[i] = M_t[i,:] @ m + G_t[i,:] @ o   (partial per p4, shfl-reduce)
    float acc = 0.0f;
    {
      const int j0 = p4 * 16;
#pragma unroll
      for (int c = 0; c < 16; c += 4) {
        float4 mm = *(const float4*)(Mt + i*SD + j0 + c);
        float4 vv = *(const float4*)(msh + j0 + c);
        acc += mm.x*vv.x + mm.y*vv.y + mm.z*vv.z + mm.w*vv.w;
      }
      const int v0 = p4 * 8;
#pragma unroll
      for (int c = 0; c < 8; c += 4) {
        float4 gg = *(const float4*)(Gt + i*NV + v0 + c);
        float4 oo = *(const float4*)(ov + v0 + c);
        acc += gg.x*oo.x + gg.y*oo.y + gg.z*oo.z + gg.w*oo.w;
      }
    }
    acc += __shfl_xor(acc, 1);
    acc += __shfl_xor(acc, 2);
    if (p4 == 0) mn[i] = acc;
    __syncthreads();

    // y[v] = H[v,:] @ m_new  (partial per p8, shfl-reduce)
    float ys = 0.0f;
    {
      const int j0 = p8 * 8;
#pragma unroll
      for (int c = 0; c < 8; c += 4) {
        float4 hh = *(const float4*)(Hs + v*SD + j0 + c);
        float4 vv = *(const float4*)(mn + j0 + c);
        ys += hh.x*vv.x + hh.y*vv.y + hh.z*vv.z + hh.w*vv.w;
      }
    }
    ys += __shfl_xor(ys, 1);
    ys += __shfl_xor(ys, 2);
    ys += __shfl_xor(ys, 4);
    if (p8 == 0) ybuf[v*TSZ + t + 1] = ys;
    if (tid < SD) msh[tid] = mn[tid];
    __syncthreads();
  }

  // coalesced write-back of this batch's [NV, TSZ] slab
  for (int s4 = tid * 4; s4 < NV*TSZ; s4 += 1024)
    *(float4*)(out + (size_t)b*NV*TSZ + s4) = *(const float4*)(ybuf + s4);
}

extern "C" void kernel_launch(void* const* d_in, const int* in_sizes, int n_in,
                              void* d_out, int out_size, void* d_ws, size_t ws_size,
                              hipStream_t stream) {
  const float* x = (const float*)d_in[0];
  const float* F = (const float*)d_in[1];
  const float* H = (const float*)d_in[2];
  const float* R = (const float*)d_in[3];
  const float* Q = (const float*)d_in[4];
  float* out = (float*)d_out;
  float* ws  = (float*)d_ws;   // needs ~3.1 MB

  hipLaunchKernelGGL(kf_phase1, dim3(1), dim3(256), 0, stream, F, H, R, Q, ws);
  hipLaunchKernelGGL(kf_phase2, dim3(BSZ), dim3(256), 0, stream, x, H, ws, out);
}

// Round 2
// 505.057 us; speedup vs baseline: 13.9361x; 13.9361x over previous
//
#include <hip/hip_runtime.h>

// Kalman filter forward. out[b,v,t] (t>=1) = H m_t,
//   m_{t+1} = M_t m_t + G_t x[:,:,t],  M_t = F(I-K_t H), G_t = F K_t.
// K_t is batch-independent (P0 = I for all batches). Phase 1 (1 block) runs
// the Riccati recursion; since it converges geometrically (DARE fixed point),
// we stop once max|dM|+|dG| < EPS and phase 2 clamps the coefficient index.
// GJ inverse is done on an augmented [S | H P] (=> K^T directly) with a
// bank-conflict-free LD=100 layout (R1 showed 4.6M conflict cycles in GJ).

#define SD 64
#define NV 32
#define TSZ 128
#define BSZ 128
#define NSTEP (TSZ - 1)

#define MG_STRIDE (SD*SD + SD*NV)          // 6144 floats per step: M then G
#define WS_FT  (NSTEP * MG_STRIDE)         // F^T, 4096 floats
#define WS_TC  (WS_FT + SD*SD)             // int: converged step index

// acc[r][0..3] += A[i0+r][k] * B[k][j0..j0+3], k in [0,KK)
template<int RI, int KK, int LDA, int LDB>
__device__ __forceinline__ void mm_acc(float acc[RI][4],
                                       const float* __restrict__ A, int i0,
                                       const float* __restrict__ B, int j0) {
  for (int k4 = 0; k4 < KK; k4 += 4) {
    float4 b0 = *(const float4*)(B + (k4+0)*LDB + j0);
    float4 b1 = *(const float4*)(B + (k4+1)*LDB + j0);
    float4 b2 = *(const float4*)(B + (k4+2)*LDB + j0);
    float4 b3 = *(const float4*)(B + (k4+3)*LDB + j0);
#pragma unroll
    for (int r = 0; r < RI; ++r) {
      float4 a = *(const float4*)(A + (i0+r)*LDA + k4);
      acc[r][0] += a.x*b0.x + a.y*b1.x + a.z*b2.x + a.w*b3.x;
      acc[r][1] += a.x*b0.y + a.y*b1.y + a.z*b2.y + a.w*b3.y;
      acc[r][2] += a.x*b0.z + a.y*b1.z + a.z*b2.z + a.w*b3.z;
      acc[r][3] += a.x*b0.w + a.y*b1.w + a.z*b2.w + a.w*b3.w;
    }
  }
}

__launch_bounds__(256)
__global__ void kf_phase1(const float* __restrict__ Fg,
                          const float* __restrict__ Hg,
                          const float* __restrict__ Rg,
                          const float* __restrict__ Qg,
                          float* __restrict__ ws) {
  __shared__ __align__(16) float Pm[SD*SD];     // P
  __shared__ __align__(16) float Zb[SD*SD];     // F @ P_u
  __shared__ __align__(16) float Fs[SD*68];     // F, LD 68
  __shared__ __align__(16) float Hs[NV*68];     // H, LD 68
  __shared__ __align__(16) float HPb[NV*SD];    // H @ P (= (P H^T)^T, P sym)
  __shared__ __align__(16) float Kb[SD*NV];     // K
  __shared__ __align__(16) float FKb[SD*NV];    // F @ K
  __shared__ __align__(16) float Aug[32*100];   // GJ ping
  __shared__ __align__(16) float Aug2[32*100];  // GJ pong
  __shared__ float wred[4];
  __shared__ int conv;
  const int tid = threadIdx.x;

  for (int s = tid; s < SD*SD; s += 256) {
    int i = s >> 6, j = s & 63;
    Fs[i*68 + j] = Fg[s];
    Pm[s] = (i == j) ? 1.0f : 0.0f;
    ws[WS_FT + s] = Fg[j*SD + i];        // F^T
  }
  for (int s = tid; s < NV*SD; s += 256)
    Hs[(s>>6)*68 + (s&63)] = Hg[s];
  __syncthreads();

  const float* Ftg = ws + WS_FT;
  int tcv = NSTEP - 1;

  for (int t = 0; t < NSTEP; ++t) {
    float* Mws = ws + (size_t)t * MG_STRIDE;
    float* Gws = Mws + SD*SD;
    const bool check = ((t & 3) == 3);
    float dmax = 0.0f;

    // S1: HP = H @ P  -> HPb and Aug cols [32:96)
    {
      const int i0 = (tid >> 4) * 2, j0 = (tid & 15) * 4;
      float acc[2][4] = {};
      mm_acc<2,64,68,64>(acc, Hs, i0, Pm, j0);
#pragma unroll
      for (int r = 0; r < 2; ++r) {
        float4 v = make_float4(acc[r][0], acc[r][1], acc[r][2], acc[r][3]);
        *(float4*)(HPb + (i0+r)*SD + j0) = v;
        *(float4*)(Aug + (i0+r)*100 + 32 + j0) = v;
      }
    }
    __syncthreads();

    // S2: S = HP @ H^T + R  -> Aug cols [0:32)   (NT product)
    {
      const int u = tid >> 3, j0 = (tid & 7) * 4;
      float4 rr = *(const float4*)(Rg + u*NV + j0);
      float a0 = rr.x, a1 = rr.y, a2 = rr.z, a3 = rr.w;
      for (int k4 = 0; k4 < 64; k4 += 4) {
        float4 hp = *(const float4*)(HPb + u*SD + k4);
        float4 h0 = *(const float4*)(Hs + (j0+0)*68 + k4);
        float4 h1 = *(const float4*)(Hs + (j0+1)*68 + k4);
        float4 h2 = *(const float4*)(Hs + (j0+2)*68 + k4);
        float4 h3 = *(const float4*)(Hs + (j0+3)*68 + k4);
        a0 += hp.x*h0.x + hp.y*h0.y + hp.z*h0.z + hp.w*h0.w;
        a1 += hp.x*h1.x + hp.y*h1.y + hp.z*h1.z + hp.w*h1.w;
        a2 += hp.x*h2.x + hp.y*h2.y + hp.z*h2.z + hp.w*h2.w;
        a3 += hp.x*h3.x + hp.y*h3.y + hp.z*h3.z + hp.w*h3.w;
      }
      *(float4*)(Aug + u*100 + j0) = make_float4(a0, a1, a2, a3);
    }
    __syncthreads();

    // S3: Gauss-Jordan on [S | HP] (SPD, no pivoting) -> K^T in cols [32:96)
    {
      const int r = tid >> 3, q = tid & 7;
      for (int p = 0; p < 32; ++p) {
        const float* X = (p & 1) ? Aug2 : Aug;
        float*       Y = (p & 1) ? Aug : Aug2;
        const float invp = 1.0f / X[p*100 + p];
        if (r == p) {
#pragma unroll
          for (int k = 0; k < 3; ++k) {
            float4 v = *(const float4*)(X + p*100 + 4*q + 32*k);
            v.x *= invp; v.y *= invp; v.z *= invp; v.w *= invp;
            *(float4*)(Y + p*100 + 4*q + 32*k) = v;
          }
        } else {
          const float f = X[r*100 + p] * invp;
#pragma unroll
          for (int k = 0; k < 3; ++k) {
            float4 xp = *(const float4*)(X + p*100 + 4*q + 32*k);
            float4 xo = *(const float4*)(X + r*100 + 4*q + 32*k);
            xo.x -= f*xp.x; xo.y -= f*xp.y; xo.z -= f*xp.z; xo.w -= f*xp.w;
            *(float4*)(Y + r*100 + 4*q + 32*k) = xo;
          }
        }
        __syncthreads();
      }
    } // 32 pivots (even) -> result in Aug

    // S4: Kb[i][r] = K^T[r][i]
    for (int s = tid; s < SD*NV; s += 256) {
      int i = s >> 5, r2 = s & 31;
      Kb[i*NV + r2] = Aug[r2*100 + 32 + i];
    }
    __syncthreads();

    // S5: P -= K @ HP   (in place)
    {
      const int i0 = (tid >> 4) * 4, j0 = (tid & 15) * 4;
      float acc[4][4] = {};
      mm_acc<4,32,32,64>(acc, Kb, i0, HPb, j0);
#pragma unroll
      for (int r = 0; r < 4; ++r) {
        float4 pv = *(const float4*)(Pm + (i0+r)*SD + j0);
        pv.x -= acc[r][0]; pv.y -= acc[r][1]; pv.z -= acc[r][2]; pv.w -= acc[r][3];
        *(float4*)(Pm + (i0+r)*SD + j0) = pv;
      }
    }
    __syncthreads();

    // S6: Z = F @ P_u
    {
      const int i0 = (tid >> 4) * 4, j0 = (tid & 15) * 4;
      float acc[4][4] = {};
      mm_acc<4,64,68,64>(acc, Fs, i0, Pm, j0);
#pragma unroll
      for (int r = 0; r < 4; ++r)
        *(float4*)(Zb + (i0+r)*SD + j0) =
            make_float4(acc[r][0], acc[r][1], acc[r][2], acc[r][3]);
    }
    __syncthreads();

    // S7: P = Z @ F^T + Q
    {
      const int i0 = (tid >> 4) * 4, j0 = (tid & 15) * 4;
      float acc[4][4];
#pragma unroll
      for (int r = 0; r < 4; ++r) {
        float4 qv = *(const float4*)(Qg + (i0+r)*SD + j0);
        acc[r][0] = qv.x; acc[r][1] = qv.y; acc[r][2] = qv.z; acc[r][3] = qv.w;
      }
      mm_acc<4,64,64,64>(acc, Zb, i0, Ftg, j0);
#pragma unroll
      for (int r = 0; r < 4; ++r)
        *(float4*)(Pm + (i0+r)*SD + j0) =
            make_float4(acc[r][0], acc[r][1], acc[r][2], acc[r][3]);
    }
    __syncthreads();

    // S8: FK = F @ K -> FKb, G_t -> ws (+ convergence diff)
    {
      const int i0 = (tid >> 3) * 2, j0 = (tid & 7) * 4;
      float acc[2][4] = {};
      mm_acc<2,64,68,32>(acc, Fs, i0, Kb, j0);
#pragma unroll
      for (int r = 0; r < 2; ++r) {
        float4 w = make_float4(acc[r][0], acc[r][1], acc[r][2], acc[r][3]);
        *(float4*)(FKb + (i0+r)*NV + j0) = w;
        *(float4*)(Gws + (i0+r)*NV + j0) = w;
        if (check) {
          float4 o = *(const float4*)(Gws - MG_STRIDE + (i0+r)*NV + j0);
          dmax = fmaxf(dmax, fmaxf(fmaxf(fabsf(w.x-o.x), fabsf(w.y-o.y)),
                                   fmaxf(fabsf(w.z-o.z), fabsf(w.w-o.w))));
        }
      }
    }
    __syncthreads();

    // S9: M_t = F - FK @ H -> ws (+ diff, reduce)
    {
      const int i0 = (tid >> 4) * 4, j0 = (tid & 15) * 4;
      float acc[4][4] = {};
      mm_acc<4,32,32,68>(acc, FKb, i0, Hs, j0);
#pragma unroll
      for (int r = 0; r < 4; ++r) {
        float4 fv = *(const float4*)(Fs + (i0+r)*68 + j0);
        fv.x -= acc[r][0]; fv.y -= acc[r][1]; fv.z -= acc[r][2]; fv.w -= acc[r][3];
        *(float4*)(Mws + (i0+r)*SD + j0) = fv;
        if (check) {
          float4 o = *(const float4*)(Mws - MG_STRIDE + (i0+r)*SD + j0);
          dmax = fmaxf(dmax, fmaxf(fmaxf(fabsf(fv.x-o.x), fabsf(fv.y-o.y)),
                                   fmaxf(fabsf(fv.z-o.z), fabsf(fv.w-o.w))));
        }
      }
    }
    if (check) {
#pragma unroll
      for (int off = 32; off >= 1; off >>= 1)
        dmax = fmaxf(dmax, __shfl_xor(dmax, off));
      if ((tid & 63) == 0) wred[tid >> 6] = dmax;
    }
    __syncthreads();
    if (check) {
      if (tid == 0)
        conv = (fmaxf(fmaxf(wred[0], wred[1]), fmaxf(wred[2], wred[3])) < 3e-5f) ? 1 : 0;
      __syncthreads();
      if (conv) { tcv = t; break; }
    }
  }
  if (tid == 0) ((int*)ws)[WS_TC] = tcv;
}

__launch_bounds__(256)
__global__ void kf_phase2(const float* __restrict__ x,
                          const float* __restrict__ Hg,
                          const float* __restrict__ ws,
                          float* __restrict__ out) {
  __shared__ __align__(16) float Hs2[NV*65];   // H, LD 65 (conflict-free y-dot)
  __shared__ __align__(16) float xt[TSZ*36];   // x[b] transposed, LD 36
  __shared__ __align__(16) float yb[NV*129];   // output slab, LD 129
  __shared__ __align__(16) float mbuf[2*SD];   // m ping-pong
  const int tid = threadIdx.x, b = blockIdx.x;

  for (int s = tid; s < NV*SD; s += 256) Hs2[(s>>6)*65 + (s&63)] = Hg[s];
  for (int s = tid; s < NV*TSZ; s += 256) {
    int v = s >> 7, t = s & 127;
    xt[t*36 + v] = x[(size_t)b*NV*TSZ + s];
  }
  if (tid < NV) yb[tid*129] = 0.0f;            // out[:, :, 0] = 0
  if (tid < 2*SD) mbuf[tid] = 0.0f;            // m_0 = 0
  const int tcv = ((const int*)ws)[WS_TC];
  __syncthreads();

  const int i = tid >> 2, p4 = tid & 3;        // m rows: 4 threads per row
  const int v = tid >> 3, p8 = tid & 7;        // y rows: 8 threads per row

  for (int t = 0; t < NSTEP; ++t) {
    const int tmin = t < tcv ? t : tcv;
    const float* Mt = ws + (size_t)tmin * MG_STRIDE;
    const float* Gt = Mt + SD*SD;
    const float* cur = mbuf + (t & 1) * SD;
    float*       nxt = mbuf + ((t + 1) & 1) * SD;

    // m_{t+1}[i] partial over p4 (M·m: 16 cols, G·o: 8 cols)
    float acc = 0.0f;
    {
      const int j0 = p4 * 16;
#pragma unroll
      for (int c = 0; c < 16; c += 4) {
        float4 mm = *(const float4*)(Mt + i*SD + j0 + c);
        float4 vv = *(const float4*)(cur + j0 + c);
        acc += mm.x*vv.x + mm.y*vv.y + mm.z*vv.z + mm.w*vv.w;
      }
      const int v0 = p4 * 8;
      const float* ov = xt + t*36;
#pragma unroll
      for (int c = 0; c < 8; c += 4) {
        float4 gg = *(const float4*)(Gt + i*NV + v0 + c);
        float4 oo = *(const float4*)(ov + v0 + c);
        acc += gg.x*oo.x + gg.y*oo.y + gg.z*oo.z + gg.w*oo.w;
      }
    }
    acc += __shfl_xor(acc, 1);
    acc += __shfl_xor(acc, 2);

    // y_t = H m_t (concurrent with the m-update; reads only cur)
    if (t >= 1) {
      float ys = 0.0f;
#pragma unroll
      for (int j = 0; j < 8; ++j)
        ys += Hs2[v*65 + p8*8 + j] * cur[p8*8 + j];
      ys += __shfl_xor(ys, 1);
      ys += __shfl_xor(ys, 2);
      ys += __shfl_xor(ys, 4);
      if (p8 == 0) yb[v*129 + t] = ys;
    }
    if (p4 == 0) nxt[i] = acc;
    __syncthreads();
  }

  // y_127 from m_127 (in mbuf[127&1] = mbuf+64)
  {
    const float* cur = mbuf + SD;
    float ys = 0.0f;
#pragma unroll
    for (int j = 0; j < 8; ++j)
      ys += Hs2[v*65 + p8*8 + j] * cur[p8*8 + j];
    ys += __shfl_xor(ys, 1);
    ys += __shfl_xor(ys, 2);
    ys += __shfl_xor(ys, 4);
    if (p8 == 0) yb[v*129 + (TSZ-1)] = ys;
  }
  __syncthreads();

  for (int s = tid; s < NV*TSZ; s += 256)
    out[(size_t)b*NV*TSZ + s] = yb[(s>>7)*129 + (s&127)];
}

extern "C" void kernel_launch(void* const* d_in, const int* in_sizes, int n_in,
                              void* d_out, int out_size, void* d_ws, size_t ws_size,
                              hipStream_t stream) {
  const float* x = (const float*)d_in[0];
  const float* F = (const float*)d_in[1];
  const float* H = (const float*)d_in[2];
  const float* R = (const float*)d_in[3];
  const float* Q = (const float*)d_in[4];
  float* out = (float*)d_out;
  float* ws  = (float*)d_ws;   // ~3.07 MB used

  hipLaunchKernelGGL(kf_phase1, dim3(1), dim3(256), 0, stream, F, H, R, Q, ws);
  hipLaunchKernelGGL(kf_phase2, dim3(BSZ), dim3(256), 0, stream, x, H, ws, out);
}

// Round 3
// 462.874 us; speedup vs baseline: 15.2061x; 1.0911x over previous
//
#include <hip/hip_runtime.h>

// Kalman filter forward. out[b,v,t] (t>=1) = H m_t,
//   m_{t+1} = M_t m_t + G_t x[:,:,t],  M_t = F(I-K_t H), G_t = F K_t.
// K_t is batch-independent (P0 = I for all batches). Phase 1 (1 block) runs
// the Riccati recursion with early stop at DARE convergence; phase 2 clamps
// the coefficient index. R3: phase-1 matmuls use split-bf16 MFMA
// (X = Xhi + Xlo, 3 mfma_f32_16x16x32_bf16 per product). Operands stored in
// LDS as (hi<<16|lo)-packed u32; A read row-major, B read B^T-row-major
// (P symmetric; HP^T/K/K^T/FK written in consumer layout at producer time).
// GJ inverse kept verbatim from R2 (fp32, known-correct).

#define SD 64
#define NV 32
#define TSZ 128
#define BSZ 128
#define NSTEP (TSZ - 1)

#define MG_STRIDE (SD*SD + SD*NV)          // 6144 floats per step: M then G
#define WS_TC  (NSTEP * MG_STRIDE + SD*SD) // int: converged step index

typedef __attribute__((ext_vector_type(8))) short bf16x8;
typedef __attribute__((ext_vector_type(4))) float f32x4;

// pack fp32 -> (bf16_hi << 16) | bf16_lo   (RNE both)
__device__ __forceinline__ unsigned packhl(float v) {
  unsigned b = __float_as_uint(v);
  unsigned hi = (b + 0x7FFFu + ((b >> 16) & 1u)) & 0xFFFF0000u;
  float lo = v - __uint_as_float(hi);
  unsigned lb = __float_as_uint(lo);
  unsigned lo16 = ((lb + 0x7FFFu + ((lb >> 16) & 1u)) >> 16);
  return hi | (lo16 & 0xFFFFu);
}

__device__ __forceinline__ float unpackf(unsigned u) {
  return __uint_as_float(u & 0xFFFF0000u) + __uint_as_float(u << 16);
}

__device__ __forceinline__ void frags_from(const unsigned* __restrict__ p,
                                           bf16x8& hi, bf16x8& lo) {
  uint4 a = *(const uint4*)p;
  uint4 b = *(const uint4*)(p + 4);
  unsigned u0=a.x,u1=a.y,u2=a.z,u3=a.w,u4=b.x,u5=b.y,u6=b.z,u7=b.w;
  hi[0]=(short)(u0>>16); hi[1]=(short)(u1>>16); hi[2]=(short)(u2>>16); hi[3]=(short)(u3>>16);
  hi[4]=(short)(u4>>16); hi[5]=(short)(u5>>16); hi[6]=(short)(u6>>16); hi[7]=(short)(u7>>16);
  lo[0]=(short)(u0&0xFFFFu); lo[1]=(short)(u1&0xFFFFu); lo[2]=(short)(u2&0xFFFFu); lo[3]=(short)(u3&0xFFFFu);
  lo[4]=(short)(u4&0xFFFFu); lo[5]=(short)(u5&0xFFFFu); lo[6]=(short)(u6&0xFFFFu); lo[7]=(short)(u7&0xFFFFu);
}

// c += A*B over 32 k-elements with split-bf16 (3 mfma, lo*lo dropped)
__device__ __forceinline__ f32x4 mfma3(const unsigned* __restrict__ ap,
                                       const unsigned* __restrict__ bp, f32x4 c) {
  bf16x8 ah, al, bh, bl;
  frags_from(ap, ah, al);
  frags_from(bp, bh, bl);
  c = __builtin_amdgcn_mfma_f32_16x16x32_bf16(ah, bh, c, 0, 0, 0);
  c = __builtin_amdgcn_mfma_f32_16x16x32_bf16(ah, bl, c, 0, 0, 0);
  c = __builtin_amdgcn_mfma_f32_16x16x32_bf16(al, bh, c, 0, 0, 0);
  return c;
}

__launch_bounds__(256)
__global__ void kf_phase1(const float* __restrict__ Fg,
                          const float* __restrict__ Hg,
                          const float* __restrict__ Rg,
                          const float* __restrict__ Qg,
                          float* __restrict__ ws) {
  // packed u32 (hi|lo bf16) operand arrays
  __shared__ unsigned Fb [64*68];   // F row-major (A-src; also B^T-src for Z*F^T)
  __shared__ unsigned Pb [64*68];   // P / Pu / Pnew (symmetric: A- and B^T-src)
  __shared__ unsigned Zbu[64*68];   // Z = F*Pu
  __shared__ unsigned Hb [32*68];   // H row-major
  __shared__ unsigned Htb[64*36];   // H^T row-major (B^T-src for FK*H)
  __shared__ unsigned Krb[64*36];   // -K row-major (A-src for K*HP)
  __shared__ unsigned Ktb[32*68];   // K^T row-major (B^T-src for F*K)
  __shared__ unsigned FKb[64*36];   // -FK row-major (A-src for FK*H)
  __shared__ unsigned HPr[32*68];   // HP row-major (A-src for HP*H^T)
  __shared__ unsigned PHt[64*36];   // (HP)^T row-major (B^T-src for K*HP)
  __shared__ __align__(16) float Aug [32*100];  // GJ ping  [S | HP]
  __shared__ __align__(16) float Aug2[32*100];  // GJ pong
  __shared__ float wred[4];
  __shared__ int conv;

  const int tid = threadIdx.x;
  const int w = tid >> 6, lane = tid & 63, quad = lane >> 4, l16 = lane & 15;

  // ---- prep: pack F, H, H^T; P = I ----
  for (int s = tid; s < SD*SD; s += 256) {
    int i = s >> 6, j = s & 63;
    Fb[i*68 + j] = packhl(Fg[s]);
    Pb[i*68 + j] = packhl((i == j) ? 1.0f : 0.0f);
  }
  for (int s = tid; s < NV*SD; s += 256) {
    int v = s >> 6, j = s & 63;
    Hb[v*68 + j] = packhl(Hg[s]);
  }
  for (int s = tid; s < SD*NV; s += 256) {
    int j = s >> 5, v = s & 31;                 // Htb[j][v] = H[v][j]
    Htb[j*36 + v] = packhl(Hg[v*SD + j]);
  }
  __syncthreads();

  int tcv = NSTEP - 1;

  for (int t = 0; t < NSTEP; ++t) {
    float* Mws = ws + (size_t)t * MG_STRIDE;
    float* Gws = Mws + SD*SD;
    const bool chk = (t >= 3) && ((t & 1) == 1);
    float dmax = 0.0f;

    // S1: HP = H @ P  (A=H, B^T-src=P sym). out: Aug RHS fp32, HPr, PHt.
    for (int tt = w; tt < 8; tt += 4) {
      const int m0 = (tt >> 2) << 4, n0 = (tt & 3) << 4;
      f32x4 c = {0.f, 0.f, 0.f, 0.f};
      c = mfma3(Hb + (m0+l16)*68 +      quad*8, Pb + (n0+l16)*68 +      quad*8, c);
      c = mfma3(Hb + (m0+l16)*68 + 32 + quad*8, Pb + (n0+l16)*68 + 32 + quad*8, c);
      unsigned pk0, pk1, pk2, pk3;
      {
        int cc = n0 + l16;
        int r0 = m0 + quad*4;
        Aug[(r0+0)*100 + 32 + cc] = c[0];
        Aug[(r0+1)*100 + 32 + cc] = c[1];
        Aug[(r0+2)*100 + 32 + cc] = c[2];
        Aug[(r0+3)*100 + 32 + cc] = c[3];
        pk0 = packhl(c[0]); pk1 = packhl(c[1]); pk2 = packhl(c[2]); pk3 = packhl(c[3]);
        HPr[(r0+0)*68 + cc] = pk0;
        HPr[(r0+1)*68 + cc] = pk1;
        HPr[(r0+2)*68 + cc] = pk2;
        HPr[(r0+3)*68 + cc] = pk3;
        *(uint4*)(PHt + cc*36 + r0) = make_uint4(pk0, pk1, pk2, pk3);
      }
    }
    __syncthreads();

    // S2: S = HP @ H^T + R  (A=HPr, B^T-src=H). out: Aug cols [0:32) fp32.
    {
      const int m0 = (w >> 1) << 4, n0 = (w & 1) << 4;
      f32x4 c;
      const int r0 = m0 + quad*4, cc = n0 + l16;
      c[0] = Rg[(r0+0)*NV + cc];
      c[1] = Rg[(r0+1)*NV + cc];
      c[2] = Rg[(r0+2)*NV + cc];
      c[3] = Rg[(r0+3)*NV + cc];
      c = mfma3(HPr + (m0+l16)*68 +      quad*8, Hb + (n0+l16)*68 +      quad*8, c);
      c = mfma3(HPr + (m0+l16)*68 + 32 + quad*8, Hb + (n0+l16)*68 + 32 + quad*8, c);
      Aug[(r0+0)*100 + cc] = c[0];
      Aug[(r0+1)*100 + cc] = c[1];
      Aug[(r0+2)*100 + cc] = c[2];
      Aug[(r0+3)*100 + cc] = c[3];
    }
    __syncthreads();

    // S3: Gauss-Jordan on [S | HP] (SPD, no pivoting) -> K^T in cols [32:96)
    {
      const int r = tid >> 3, q = tid & 7;
      for (int p = 0; p < 32; ++p) {
        const float* X = (p & 1) ? Aug2 : Aug;
        float*       Y = (p & 1) ? Aug : Aug2;
        const float invp = 1.0f / X[p*100 + p];
        if (r == p) {
#pragma unroll
          for (int k = 0; k < 3; ++k) {
            float4 v = *(const float4*)(X + p*100 + 4*q + 32*k);
            v.x *= invp; v.y *= invp; v.z *= invp; v.w *= invp;
            *(float4*)(Y + p*100 + 4*q + 32*k) = v;
          }
        } else {
          const float f = X[r*100 + p] * invp;
#pragma unroll
          for (int k = 0; k < 3; ++k) {
            float4 xp = *(const float4*)(X + p*100 + 4*q + 32*k);
            float4 xo = *(const float4*)(X + r*100 + 4*q + 32*k);
            xo.x -= f*xp.x; xo.y -= f*xp.y; xo.z -= f*xp.z; xo.w -= f*xp.w;
            *(float4*)(Y + r*100 + 4*q + 32*k) = xo;
          }
        }
        __syncthreads();
      }
    } // result in Aug; K^T = cols [32:96)

    // S4: pack K (negated, row-major) and K^T (row-major)
    for (int s = tid; s < SD*NV; s += 256) {
      int i = s >> 5, r2 = s & 31;
      float kv = Aug[r2*100 + 32 + i];
      Krb[i*36 + r2] = packhl(-kv);
      Ktb[r2*68 + i] = packhl(kv);
    }
    __syncthreads();

    // S5 || S8:  Pu = P - K*HP  (16 tiles)  ||  FK = F*K, G_t out (8 tiles)
    for (int tt = w; tt < 24; tt += 4) {
      if (tt < 16) {
        const int m0 = (tt >> 2) << 4, n0 = (tt & 3) << 4;
        const int r0 = m0 + quad*4, cc = n0 + l16;
        f32x4 c;
        c[0] = unpackf(Pb[(r0+0)*68 + cc]);
        c[1] = unpackf(Pb[(r0+1)*68 + cc]);
        c[2] = unpackf(Pb[(r0+2)*68 + cc]);
        c[3] = unpackf(Pb[(r0+3)*68 + cc]);
        c = mfma3(Krb + (m0+l16)*36 + quad*8, PHt + (n0+l16)*36 + quad*8, c);
        Pb[(r0+0)*68 + cc] = packhl(c[0]);
        Pb[(r0+1)*68 + cc] = packhl(c[1]);
        Pb[(r0+2)*68 + cc] = packhl(c[2]);
        Pb[(r0+3)*68 + cc] = packhl(c[3]);
      } else {
        const int ss = tt - 16;
        const int m0 = (ss >> 1) << 4, n0 = (ss & 1) << 4;
        f32x4 c = {0.f, 0.f, 0.f, 0.f};
        c = mfma3(Fb + (m0+l16)*68 +      quad*8, Ktb + (n0+l16)*68 +      quad*8, c);
        c = mfma3(Fb + (m0+l16)*68 + 32 + quad*8, Ktb + (n0+l16)*68 + 32 + quad*8, c);
        const int r0 = m0 + quad*4, cc = n0 + l16;
#pragma unroll
        for (int g = 0; g < 4; ++g) {
          float gv = c[g];
          Gws[(r0+g)*NV + cc] = gv;
          FKb[(r0+g)*36 + cc] = packhl(-gv);
          if (chk) {
            float o = *(Gws - MG_STRIDE + (r0+g)*NV + cc);
            dmax = fmaxf(dmax, fabsf(gv - o));
          }
        }
      }
    }
    __syncthreads();

    // S6 || S9:  Z = F*Pu (16 tiles)  ||  M = F - FK*H -> ws (16 tiles)
    for (int tt = w; tt < 32; tt += 4) {
      if (tt < 16) {
        const int m0 = (tt >> 2) << 4, n0 = (tt & 3) << 4;
        f32x4 c = {0.f, 0.f, 0.f, 0.f};
        c = mfma3(Fb + (m0+l16)*68 +      quad*8, Pb + (n0+l16)*68 +      quad*8, c);
        c = mfma3(Fb + (m0+l16)*68 + 32 + quad*8, Pb + (n0+l16)*68 + 32 + quad*8, c);
        const int r0 = m0 + quad*4, cc = n0 + l16;
        Zbu[(r0+0)*68 + cc] = packhl(c[0]);
        Zbu[(r0+1)*68 + cc] = packhl(c[1]);
        Zbu[(r0+2)*68 + cc] = packhl(c[2]);
        Zbu[(r0+3)*68 + cc] = packhl(c[3]);
      } else {
        const int ss = tt - 16;
        const int m0 = (ss >> 2) << 4, n0 = (ss & 3) << 4;
        const int r0 = m0 + quad*4, cc = n0 + l16;
        f32x4 c;
        c[0] = Fg[(r0+0)*SD + cc];
        c[1] = Fg[(r0+1)*SD + cc];
        c[2] = Fg[(r0+2)*SD + cc];
        c[3] = Fg[(r0+3)*SD + cc];
        c = mfma3(FKb + (m0+l16)*36 + quad*8, Htb + (n0+l16)*36 + quad*8, c);
#pragma unroll
        for (int g = 0; g < 4; ++g) {
          float mv = c[g];
          Mws[(r0+g)*SD + cc] = mv;
          if (chk) {
            float o = *(Mws - MG_STRIDE + (r0+g)*SD + cc);
            dmax = fmaxf(dmax, fabsf(mv - o));
          }
        }
      }
    }
    __syncthreads();

    // S7: P = Z*F^T + Q  (A=Z, B^T-src=F row-major)
    for (int tt = w; tt < 16; tt += 4) {
      const int m0 = (tt >> 2) << 4, n0 = (tt & 3) << 4;
      const int r0 = m0 + quad*4, cc = n0 + l16;
      f32x4 c;
      c[0] = Qg[(r0+0)*SD + cc];
      c[1] = Qg[(r0+1)*SD + cc];
      c[2] = Qg[(r0+2)*SD + cc];
      c[3] = Qg[(r0+3)*SD + cc];
      c = mfma3(Zbu + (m0+l16)*68 +      quad*8, Fb + (n0+l16)*68 +      quad*8, c);
      c = mfma3(Zbu + (m0+l16)*68 + 32 + quad*8, Fb + (n0+l16)*68 + 32 + quad*8, c);
      Pb[(r0+0)*68 + cc] = packhl(c[0]);
      Pb[(r0+1)*68 + cc] = packhl(c[1]);
      Pb[(r0+2)*68 + cc] = packhl(c[2]);
      Pb[(r0+3)*68 + cc] = packhl(c[3]);
    }

    if (chk) {
#pragma unroll
      for (int off = 32; off >= 1; off >>= 1)
        dmax = fmaxf(dmax, __shfl_xor(dmax, off));
      if ((tid & 63) == 0) wred[tid >> 6] = dmax;
    }
    __syncthreads();
    if (chk) {
      if (tid == 0)
        conv = (fmaxf(fmaxf(wred[0], wred[1]), fmaxf(wred[2], wred[3])) < 3e-5f) ? 1 : 0;
      __syncthreads();
      if (conv) { tcv = t; break; }
    }
  }
  if (tid == 0) ((int*)ws)[WS_TC] = tcv;
}

__launch_bounds__(256)
__global__ void kf_phase2(const float* __restrict__ x,
                          const float* __restrict__ Hg,
                          const float* __restrict__ ws,
                          float* __restrict__ out) {
  __shared__ __align__(16) float Hs2[NV*65];   // H, LD 65 (conflict-free y-dot)
  __shared__ __align__(16) float xt[TSZ*36];   // x[b] transposed, LD 36
  __shared__ __align__(16) float yb[NV*129];   // output slab, LD 129
  __shared__ __align__(16) float mbuf[2*SD];   // m ping-pong
  const int tid = threadIdx.x, b = blockIdx.x;

  for (int s = tid; s < NV*SD; s += 256) Hs2[(s>>6)*65 + (s&63)] = Hg[s];
  for (int s = tid; s < NV*TSZ; s += 256) {
    int v = s >> 7, t = s & 127;
    xt[t*36 + v] = x[(size_t)b*NV*TSZ + s];
  }
  if (tid < NV) yb[tid*129] = 0.0f;            // out[:, :, 0] = 0
  if (tid < 2*SD) mbuf[tid] = 0.0f;            // m_0 = 0
  const int tcv = ((const int*)ws)[WS_TC];
  __syncthreads();

  const int i = tid >> 2, p4 = tid & 3;        // m rows: 4 threads per row
  const int v = tid >> 3, p8 = tid & 7;        // y rows: 8 threads per row

  for (int t = 0; t < NSTEP; ++t) {
    const int tmin = t < tcv ? t : tcv;
    const float* Mt = ws + (size_t)tmin * MG_STRIDE;
    const float* Gt = Mt + SD*SD;
    const float* cur = mbuf + (t & 1) * SD;
    float*       nxt = mbuf + ((t + 1) & 1) * SD;

    // m_{t+1}[i] partial over p4 (M·m: 16 cols, G·o: 8 cols)
    float acc = 0.0f;
    {
      const int j0 = p4 * 16;
#pragma unroll
      for (int c = 0; c < 16; c += 4) {
        float4 mm = *(const float4*)(Mt + i*SD + j0 + c);
        float4 vv = *(const float4*)(cur + j0 + c);
        acc += mm.x*vv.x + mm.y*vv.y + mm.z*vv.z + mm.w*vv.w;
      }
      const int v0 = p4 * 8;
      const float* ov = xt + t*36;
#pragma unroll
      for (int c = 0; c < 8; c += 4) {
        float4 gg = *(const float4*)(Gt + i*NV + v0 + c);
        float4 oo = *(const float4*)(ov + v0 + c);
        acc += gg.x*oo.x + gg.y*oo.y + gg.z*oo.z + gg.w*oo.w;
      }
    }
    acc += __shfl_xor(acc, 1);
    acc += __shfl_xor(acc, 2);

    // y_t = H m_t (concurrent with the m-update; reads only cur)
    if (t >= 1) {
      float ys = 0.0f;
#pragma unroll
      for (int j = 0; j < 8; ++j)
        ys += Hs2[v*65 + p8*8 + j] * cur[p8*8 + j];
      ys += __shfl_xor(ys, 1);
      ys += __shfl_xor(ys, 2);
      ys += __shfl_xor(ys, 4);
      if (p8 == 0) yb[v*129 + t] = ys;
    }
    if (p4 == 0) nxt[i] = acc;
    __syncthreads();
  }

  // y_127 from m_127 (in mbuf[127&1] = mbuf+64)
  {
    const float* cur = mbuf + SD;
    float ys = 0.0f;
#pragma unroll
    for (int j = 0; j < 8; ++j)
      ys += Hs2[v*65 + p8*8 + j] * cur[p8*8 + j];
    ys += __shfl_xor(ys, 1);
    ys += __shfl_xor(ys, 2);
    ys += __shfl_xor(ys, 4);
    if (p8 == 0) yb[v*129 + (TSZ-1)] = ys;
  }
  __syncthreads();

  for (int s = tid; s < NV*TSZ; s += 256)
    out[(size_t)b*NV*TSZ + s] = yb[(s>>7)*129 + (s&127)];
}

extern "C" void kernel_launch(void* const* d_in, const int* in_sizes, int n_in,
                              void* d_out, int out_size, void* d_ws, size_t ws_size,
                              hipStream_t stream) {
  const float* x = (const float*)d_in[0];
  const float* F = (const float*)d_in[1];
  const float* H = (const float*)d_in[2];
  const float* R = (const float*)d_in[3];
  const float* Q = (const float*)d_in[4];
  float* out = (float*)d_out;
  float* ws  = (float*)d_ws;   // ~3.1 MB used

  hipLaunchKernelGGL(kf_phase1, dim3(1), dim3(256), 0, stream, F, H, R, Q, ws);
  hipLaunchKernelGGL(kf_phase2, dim3(BSZ), dim3(256), 0, stream, x, H, ws, out);
}

// Round 4
// 339.557 us; speedup vs baseline: 20.7286x; 1.3632x over previous
//
#include <hip/hip_runtime.h>

// Kalman filter forward. out[b,v,t] (t>=1) = H m_t,
//   m_{t+1} = M_t m_t + G_t x[:,:,t],  M_t = F(I-K_t H), G_t = F K_t.
// K_t is batch-independent (P0 = I for all batches).
// Phase 1 (1 block): Riccati recursion, early stop at DARE convergence.
//   R4: S^-1 via warm-started Newton-Schulz (t>=3) instead of 32-pivot GJ
//   (R3 showed the step is barrier-latency bound: ~38 phases/step, GJ = 32).
//   GJ kept for t<3 (large dS => Newton unsafe); X_2 = R^-1(I - H K_2).
//   Epilogue computes M^2, MG, HM, HG of the converged system for phase 2.
// Phase 2 (128 blocks): transient single steps t<tc, then PAIR steps:
//   y_t = H m_t, y_{t+1} = HM m_t + HG o_t, m_{t+2} = M^2 m_t + MG o_t + G o_{t+1}
//   -- one barrier per 2 timesteps, serial rounds 127 -> ~58.

#define SD 64
#define NV 32
#define TSZ 128
#define BSZ 128
#define NSTEP (TSZ - 1)
#define TMAX 120                            // hard cap on Riccati steps

#define MG_STRIDE (SD*SD + SD*NV)           // 6144 floats per step: M then G
#define WS_TC   (124*MG_STRIDE)             // int: converged step index
#define WS_PAIR (125*MG_STRIDE)             // M2(4096) MG(2048) HM(2048) HG(1024)

typedef __attribute__((ext_vector_type(8))) short bf16x8;
typedef __attribute__((ext_vector_type(4))) float f32x4;

// pack fp32 -> (bf16_hi << 16) | bf16_lo   (RNE both)
__device__ __forceinline__ unsigned packhl(float v) {
  unsigned b = __float_as_uint(v);
  unsigned hi = (b + 0x7FFFu + ((b >> 16) & 1u)) & 0xFFFF0000u;
  float lo = v - __uint_as_float(hi);
  unsigned lb = __float_as_uint(lo);
  unsigned lo16 = ((lb + 0x7FFFu + ((lb >> 16) & 1u)) >> 16);
  return hi | (lo16 & 0xFFFFu);
}

__device__ __forceinline__ float unpackf(unsigned u) {
  return __uint_as_float(u & 0xFFFF0000u) + __uint_as_float(u << 16);
}

__device__ __forceinline__ void frags_from(const unsigned* __restrict__ p,
                                           bf16x8& hi, bf16x8& lo) {
  uint4 a = *(const uint4*)p;
  uint4 b = *(const uint4*)(p + 4);
  unsigned u0=a.x,u1=a.y,u2=a.z,u3=a.w,u4=b.x,u5=b.y,u6=b.z,u7=b.w;
  hi[0]=(short)(u0>>16); hi[1]=(short)(u1>>16); hi[2]=(short)(u2>>16); hi[3]=(short)(u3>>16);
  hi[4]=(short)(u4>>16); hi[5]=(short)(u5>>16); hi[6]=(short)(u6>>16); hi[7]=(short)(u7>>16);
  lo[0]=(short)(u0&0xFFFFu); lo[1]=(short)(u1&0xFFFFu); lo[2]=(short)(u2&0xFFFFu); lo[3]=(short)(u3&0xFFFFu);
  lo[4]=(short)(u4&0xFFFFu); lo[5]=(short)(u5&0xFFFFu); lo[6]=(short)(u6&0xFFFFu); lo[7]=(short)(u7&0xFFFFu);
}

// c += A*B over 32 k-elements with split-bf16 (3 mfma, lo*lo dropped)
__device__ __forceinline__ f32x4 mfma3(const unsigned* __restrict__ ap,
                                       const unsigned* __restrict__ bp, f32x4 c) {
  bf16x8 ah, al, bh, bl;
  frags_from(ap, ah, al);
  frags_from(bp, bh, bl);
  c = __builtin_amdgcn_mfma_f32_16x16x32_bf16(ah, bh, c, 0, 0, 0);
  c = __builtin_amdgcn_mfma_f32_16x16x32_bf16(ah, bl, c, 0, 0, 0);
  c = __builtin_amdgcn_mfma_f32_16x16x32_bf16(al, bh, c, 0, 0, 0);
  return c;
}

__launch_bounds__(256)
__global__ void kf_phase1(const float* __restrict__ Fg,
                          const float* __restrict__ Hg,
                          const float* __restrict__ Rg,
                          const float* __restrict__ Qg,
                          float* __restrict__ ws) {
  __shared__ unsigned Fb [64*68];    // F row-major (A-src; B^T-src for Z*F^T)
  __shared__ unsigned Pb [64*68];    // P (symmetric: A- and B^T-src); epilogue: M
  __shared__ unsigned Hb [32*68];    // H row-major
  __shared__ unsigned Htb[64*36];    // H^T row-major (B^T-src for FK*H)
  __shared__ unsigned Krb[64*36];    // -K row-major (A-src for K*HP)
  __shared__ unsigned Ktb[32*68];    // K^T row-major (B^T-src for F*K); epilogue: G^T
  __shared__ unsigned FKb[64*36];    // -FK row-major (A-src for FK*H)
  __shared__ unsigned HPr[32*68];    // HP row-major (A-src for HP*H^T)
  __shared__ unsigned PHt[64*36];    // (HP)^T row-major (B^T-src)
  __shared__ unsigned Rinvb[32*36];  // R^-1 packed (A-src)
  __shared__ unsigned Xbuf[2][2][32*36]; // S^-1 ping-pong: [p][0]=row-major, [p][1]=transposed
  __shared__ unsigned Sb [32*36];    // S packed (A-src for Newton)
  __shared__ unsigned Bt2[32*36];    // (2I-T)^T / (I-HK)^T packed
  __shared__ __align__(16) float AugPool[2*3200];  // GJ ping+pong; aliased as Zbu
  __shared__ float wred[4];
  __shared__ int conv;

  float* Aug  = AugPool;
  float* Aug2 = AugPool + 3200;
  unsigned* Zbu = (unsigned*)AugPool;          // 64x68 u32, used S6->S7 only

  const int tid = threadIdx.x;
  const int w = tid >> 6, lane = tid & 63, quad = lane >> 4, l16 = lane & 15;

  // ---- prep: pack F, H, H^T; P = I ----
  for (int s = tid; s < SD*SD; s += 256) {
    int i = s >> 6, j = s & 63;
    Fb[i*68 + j] = packhl(Fg[s]);
    Pb[i*68 + j] = packhl((i == j) ? 1.0f : 0.0f);
  }
  for (int s = tid; s < NV*SD; s += 256) {
    int v = s >> 6, j = s & 63;
    Hb[v*68 + j] = packhl(Hg[s]);
  }
  for (int s = tid; s < SD*NV; s += 256) {
    int j = s >> 5, v = s & 31;
    Htb[j*36 + v] = packhl(Hg[v*SD + j]);
  }
  // ---- R^-1 via GJ on [R | I] (once) ----
  for (int s = tid; s < NV*NV; s += 256) {
    int rr = s >> 5, c = s & 31;
    Aug[rr*100 + c] = Rg[s];
    Aug[rr*100 + 32 + c] = (rr == c) ? 1.0f : 0.0f;
  }
  __syncthreads();
  {
    const int r = tid >> 3, q = tid & 7;
    for (int p = 0; p < 32; ++p) {
      const float* X = (p & 1) ? Aug2 : Aug;
      float*       Y = (p & 1) ? Aug : Aug2;
      const float invp = 1.0f / X[p*100 + p];
      if (r == p) {
#pragma unroll
        for (int k = 0; k < 2; ++k) {
          float4 v = *(const float4*)(X + p*100 + 4*q + 32*k);
          v.x *= invp; v.y *= invp; v.z *= invp; v.w *= invp;
          *(float4*)(Y + p*100 + 4*q + 32*k) = v;
        }
      } else {
        const float f = X[r*100 + p] * invp;
#pragma unroll
        for (int k = 0; k < 2; ++k) {
          float4 xp4 = *(const float4*)(X + p*100 + 4*q + 32*k);
          float4 xo = *(const float4*)(X + r*100 + 4*q + 32*k);
          xo.x -= f*xp4.x; xo.y -= f*xp4.y; xo.z -= f*xp4.z; xo.w -= f*xp4.w;
          *(float4*)(Y + r*100 + 4*q + 32*k) = xo;
        }
      }
      __syncthreads();
    }
  }
  for (int s = tid; s < NV*NV; s += 256) {
    int rr = s >> 5, c = s & 31;
    Rinvb[rr*36 + c] = packhl(Aug[rr*100 + 32 + c]);
  }
  __syncthreads();

  int tcv = TMAX - 1;
  int xp = 0;                                  // Newton X parity (uniform)

  for (int t = 0; t < TMAX; ++t) {
    float* Mws = ws + (size_t)t * MG_STRIDE;
    float* Gws = Mws + SD*SD;
    const bool chk = (t >= 3);
    float dmax = 0.0f;

    // S1: HP = H @ P (A=H, B^T-src=P sym) -> HPr, PHt (+ Aug RHS if GJ step)
    for (int tt = w; tt < 8; tt += 4) {
      const int m0 = (tt >> 2) << 4, n0 = (tt & 3) << 4;
      f32x4 c = {0.f, 0.f, 0.f, 0.f};
      c = mfma3(Hb + (m0+l16)*68 +      quad*8, Pb + (n0+l16)*68 +      quad*8, c);
      c = mfma3(Hb + (m0+l16)*68 + 32 + quad*8, Pb + (n0+l16)*68 + 32 + quad*8, c);
      const int cc = n0 + l16, r0 = m0 + quad*4;
      unsigned pk0 = packhl(c[0]), pk1 = packhl(c[1]), pk2 = packhl(c[2]), pk3 = packhl(c[3]);
      HPr[(r0+0)*68 + cc] = pk0;
      HPr[(r0+1)*68 + cc] = pk1;
      HPr[(r0+2)*68 + cc] = pk2;
      HPr[(r0+3)*68 + cc] = pk3;
      *(uint4*)(PHt + cc*36 + r0) = make_uint4(pk0, pk1, pk2, pk3);
      if (t < 3) {
        Aug[(r0+0)*100 + 32 + cc] = c[0];
        Aug[(r0+1)*100 + 32 + cc] = c[1];
        Aug[(r0+2)*100 + 32 + cc] = c[2];
        Aug[(r0+3)*100 + 32 + cc] = c[3];
      }
    }
    __syncthreads();

    // S2: S = HP @ H^T + R  -> Aug left (t<3) or Sb packed (t>=3)
    {
      const int m0 = (w >> 1) << 4, n0 = (w & 1) << 4;
      const int r0 = m0 + quad*4, cc = n0 + l16;
      f32x4 c;
      c[0] = Rg[(r0+0)*NV + cc];
      c[1] = Rg[(r0+1)*NV + cc];
      c[2] = Rg[(r0+2)*NV + cc];
      c[3] = Rg[(r0+3)*NV + cc];
      c = mfma3(HPr + (m0+l16)*68 +      quad*8, Hb + (n0+l16)*68 +      quad*8, c);
      c = mfma3(HPr + (m0+l16)*68 + 32 + quad*8, Hb + (n0+l16)*68 + 32 + quad*8, c);
      if (t < 3) {
        Aug[(r0+0)*100 + cc] = c[0];
        Aug[(r0+1)*100 + cc] = c[1];
        Aug[(r0+2)*100 + cc] = c[2];
        Aug[(r0+3)*100 + cc] = c[3];
      } else {
        Sb[(r0+0)*36 + cc] = packhl(c[0]);
        Sb[(r0+1)*36 + cc] = packhl(c[1]);
        Sb[(r0+2)*36 + cc] = packhl(c[2]);
        Sb[(r0+3)*36 + cc] = packhl(c[3]);
      }
    }
    __syncthreads();

    if (t < 3) {
      // S3: GJ on [S | HP] -> K^T in cols [32:96)
      const int r = tid >> 3, q = tid & 7;
      for (int p = 0; p < 32; ++p) {
        const float* X = (p & 1) ? Aug2 : Aug;
        float*       Y = (p & 1) ? Aug : Aug2;
        const float invp = 1.0f / X[p*100 + p];
        if (r == p) {
#pragma unroll
          for (int k = 0; k < 3; ++k) {
            float4 v = *(const float4*)(X + p*100 + 4*q + 32*k);
            v.x *= invp; v.y *= invp; v.z *= invp; v.w *= invp;
            *(float4*)(Y + p*100 + 4*q + 32*k) = v;
          }
        } else {
          const float f = X[r*100 + p] * invp;
#pragma unroll
          for (int k = 0; k < 3; ++k) {
            float4 xp4 = *(const float4*)(X + p*100 + 4*q + 32*k);
            float4 xo = *(const float4*)(X + r*100 + 4*q + 32*k);
            xo.x -= f*xp4.x; xo.y -= f*xp4.y; xo.z -= f*xp4.z; xo.w -= f*xp4.w;
            *(float4*)(Y + r*100 + 4*q + 32*k) = xo;
          }
        }
        __syncthreads();
      }
      // S4: pack -K and K^T
      for (int s = tid; s < SD*NV; s += 256) {
        int i = s >> 5, r2 = s & 31;
        float kv = Aug[r2*100 + 32 + i];
        Krb[i*36 + r2] = packhl(-kv);
        Ktb[r2*68 + i] = packhl(kv);
      }
      __syncthreads();
      if (t == 2) {
        // X_2 = R^-1 (I - H K):  HK = H@K (B^T-src = Ktb)
        {
          const int m0 = (w >> 1) << 4, n0 = (w & 1) << 4;
          f32x4 c = {0.f, 0.f, 0.f, 0.f};
          c = mfma3(Hb + (m0+l16)*68 +      quad*8, Ktb + (n0+l16)*68 +      quad*8, c);
          c = mfma3(Hb + (m0+l16)*68 + 32 + quad*8, Ktb + (n0+l16)*68 + 32 + quad*8, c);
          const int r0 = m0 + quad*4, cc = n0 + l16;
          unsigned q0 = packhl((cc == r0+0 ? 1.f : 0.f) - c[0]);
          unsigned q1 = packhl((cc == r0+1 ? 1.f : 0.f) - c[1]);
          unsigned q2 = packhl((cc == r0+2 ? 1.f : 0.f) - c[2]);
          unsigned q3 = packhl((cc == r0+3 ? 1.f : 0.f) - c[3]);
          *(uint4*)(Bt2 + cc*36 + r0) = make_uint4(q0, q1, q2, q3);
        }
        __syncthreads();
        {
          const int m0 = (w >> 1) << 4, n0 = (w & 1) << 4;
          f32x4 c = {0.f, 0.f, 0.f, 0.f};
          c = mfma3(Rinvb + (m0+l16)*36 + quad*8, Bt2 + (n0+l16)*36 + quad*8, c);
          const int r0 = m0 + quad*4, cc = n0 + l16;
          unsigned q0 = packhl(c[0]), q1 = packhl(c[1]), q2 = packhl(c[2]), q3 = packhl(c[3]);
          Xbuf[0][0][(r0+0)*36 + cc] = q0;
          Xbuf[0][0][(r0+1)*36 + cc] = q1;
          Xbuf[0][0][(r0+2)*36 + cc] = q2;
          Xbuf[0][0][(r0+3)*36 + cc] = q3;
          *(uint4*)(&Xbuf[0][1][cc*36 + r0]) = make_uint4(q0, q1, q2, q3);
        }
        xp = 0;
        __syncthreads();
      }
    } else {
      // Newton-Schulz: X' = X (2I - S X), warm start from previous step
      const int nit = (t < 5) ? 5 : ((t < 8) ? 4 : 3);
      for (int it = 0; it < nit; ++it) {
        {  // T = S @ X : write (2I - T)^T -> Bt2
          const int m0 = (w >> 1) << 4, n0 = (w & 1) << 4;
          f32x4 c = {0.f, 0.f, 0.f, 0.f};
          c = mfma3(Sb + (m0+l16)*36 + quad*8, Xbuf[xp][1] + (n0+l16)*36 + quad*8, c);
          const int r0 = m0 + quad*4, cc = n0 + l16;
          unsigned q0 = packhl((cc == r0+0 ? 2.f : 0.f) - c[0]);
          unsigned q1 = packhl((cc == r0+1 ? 2.f : 0.f) - c[1]);
          unsigned q2 = packhl((cc == r0+2 ? 2.f : 0.f) - c[2]);
          unsigned q3 = packhl((cc == r0+3 ? 2.f : 0.f) - c[3]);
          *(uint4*)(Bt2 + cc*36 + r0) = make_uint4(q0, q1, q2, q3);
        }
        __syncthreads();
        {  // X' = X @ (2I - T) -> other parity (both layouts)
          const int m0 = (w >> 1) << 4, n0 = (w & 1) << 4;
          f32x4 c = {0.f, 0.f, 0.f, 0.f};
          c = mfma3(Xbuf[xp][0] + (m0+l16)*36 + quad*8, Bt2 + (n0+l16)*36 + quad*8, c);
          const int r0 = m0 + quad*4, cc = n0 + l16;
          unsigned q0 = packhl(c[0]), q1 = packhl(c[1]), q2 = packhl(c[2]), q3 = packhl(c[3]);
          unsigned* Xr = Xbuf[xp^1][0];
          Xr[(r0+0)*36 + cc] = q0;
          Xr[(r0+1)*36 + cc] = q1;
          Xr[(r0+2)*36 + cc] = q2;
          Xr[(r0+3)*36 + cc] = q3;
          *(uint4*)(&Xbuf[xp^1][1][cc*36 + r0]) = make_uint4(q0, q1, q2, q3);
        }
        __syncthreads();
        xp ^= 1;
      }
      // K^T = X @ HP  -> Krb (-K), Ktb (K^T)
      for (int tt = w; tt < 8; tt += 4) {
        const int m0 = (tt >> 2) << 4, n0 = (tt & 3) << 4;
        f32x4 c = {0.f, 0.f, 0.f, 0.f};
        c = mfma3(Xbuf[xp][0] + (m0+l16)*36 + quad*8, PHt + (n0+l16)*36 + quad*8, c);
        const int r0 = m0 + quad*4, cc = n0 + l16;
        Ktb[(r0+0)*68 + cc] = packhl(c[0]);
        Ktb[(r0+1)*68 + cc] = packhl(c[1]);
        Ktb[(r0+2)*68 + cc] = packhl(c[2]);
        Ktb[(r0+3)*68 + cc] = packhl(c[3]);
        *(uint4*)(Krb + cc*36 + r0) =
            make_uint4(packhl(-c[0]), packhl(-c[1]), packhl(-c[2]), packhl(-c[3]));
      }
      __syncthreads();
    }

    // S5 || S8:  Pu = P - K*HP (16 tiles) || FK = F*K, G_t out (8 tiles)
    for (int tt = w; tt < 24; tt += 4) {
      if (tt < 16) {
        const int m0 = (tt >> 2) << 4, n0 = (tt & 3) << 4;
        const int r0 = m0 + quad*4, cc = n0 + l16;
        f32x4 c;
        c[0] = unpackf(Pb[(r0+0)*68 + cc]);
        c[1] = unpackf(Pb[(r0+1)*68 + cc]);
        c[2] = unpackf(Pb[(r0+2)*68 + cc]);
        c[3] = unpackf(Pb[(r0+3)*68 + cc]);
        c = mfma3(Krb + (m0+l16)*36 + quad*8, PHt + (n0+l16)*36 + quad*8, c);
        Pb[(r0+0)*68 + cc] = packhl(c[0]);
        Pb[(r0+1)*68 + cc] = packhl(c[1]);
        Pb[(r0+2)*68 + cc] = packhl(c[2]);
        Pb[(r0+3)*68 + cc] = packhl(c[3]);
      } else {
        const int ss = tt - 16;
        const int m0 = (ss >> 1) << 4, n0 = (ss & 1) << 4;
        f32x4 c = {0.f, 0.f, 0.f, 0.f};
        c = mfma3(Fb + (m0+l16)*68 +      quad*8, Ktb + (n0+l16)*68 +      quad*8, c);
        c = mfma3(Fb + (m0+l16)*68 + 32 + quad*8, Ktb + (n0+l16)*68 + 32 + quad*8, c);
        const int r0 = m0 + quad*4, cc = n0 + l16;
#pragma unroll
        for (int g = 0; g < 4; ++g) {
          float gv = c[g];
          Gws[(r0+g)*NV + cc] = gv;
          FKb[(r0+g)*36 + cc] = packhl(-gv);
          if (chk) {
            float o = *(Gws - MG_STRIDE + (r0+g)*NV + cc);
            dmax = fmaxf(dmax, fabsf(gv - o));
          }
        }
      }
    }
    __syncthreads();

    // S6 || S9:  Z = F*Pu -> Zbu (16) || M = F - FK*H -> ws (16)
    for (int tt = w; tt < 32; tt += 4) {
      if (tt < 16) {
        const int m0 = (tt >> 2) << 4, n0 = (tt & 3) << 4;
        f32x4 c = {0.f, 0.f, 0.f, 0.f};
        c = mfma3(Fb + (m0+l16)*68 +      quad*8, Pb + (n0+l16)*68 +      quad*8, c);
        c = mfma3(Fb + (m0+l16)*68 + 32 + quad*8, Pb + (n0+l16)*68 + 32 + quad*8, c);
        const int r0 = m0 + quad*4, cc = n0 + l16;
        Zbu[(r0+0)*68 + cc] = packhl(c[0]);
        Zbu[(r0+1)*68 + cc] = packhl(c[1]);
        Zbu[(r0+2)*68 + cc] = packhl(c[2]);
        Zbu[(r0+3)*68 + cc] = packhl(c[3]);
      } else {
        const int ss = tt - 16;
        const int m0 = (ss >> 2) << 4, n0 = (ss & 3) << 4;
        const int r0 = m0 + quad*4, cc = n0 + l16;
        f32x4 c;
        c[0] = Fg[(r0+0)*SD + cc];
        c[1] = Fg[(r0+1)*SD + cc];
        c[2] = Fg[(r0+2)*SD + cc];
        c[3] = Fg[(r0+3)*SD + cc];
        c = mfma3(FKb + (m0+l16)*36 + quad*8, Htb + (n0+l16)*36 + quad*8, c);
#pragma unroll
        for (int g = 0; g < 4; ++g) {
          float mv = c[g];
          Mws[(r0+g)*SD + cc] = mv;
          if (chk) {
            float o = *(Mws - MG_STRIDE + (r0+g)*SD + cc);
            dmax = fmaxf(dmax, fabsf(mv - o));
          }
        }
      }
    }
    __syncthreads();

    // S7: P = Z*F^T + Q  (B^T-src = F row-major)
    for (int tt = w; tt < 16; tt += 4) {
      const int m0 = (tt >> 2) << 4, n0 = (tt & 3) << 4;
      const int r0 = m0 + quad*4, cc = n0 + l16;
      f32x4 c;
      c[0] = Qg[(r0+0)*SD + cc];
      c[1] = Qg[(r0+1)*SD + cc];
      c[2] = Qg[(r0+2)*SD + cc];
      c[3] = Qg[(r0+3)*SD + cc];
      c = mfma3(Zbu + (m0+l16)*68 +      quad*8, Fb + (n0+l16)*68 +      quad*8, c);
      c = mfma3(Zbu + (m0+l16)*68 + 32 + quad*8, Fb + (n0+l16)*68 + 32 + quad*8, c);
      Pb[(r0+0)*68 + cc] = packhl(c[0]);
      Pb[(r0+1)*68 + cc] = packhl(c[1]);
      Pb[(r0+2)*68 + cc] = packhl(c[2]);
      Pb[(r0+3)*68 + cc] = packhl(c[3]);
    }

    if (chk) {
#pragma unroll
      for (int off = 32; off >= 1; off >>= 1)
        dmax = fmaxf(dmax, __shfl_xor(dmax, off));
      if ((tid & 63) == 0) wred[tid >> 6] = dmax;
    }
    __syncthreads();
    if (chk) {
      if (tid == 0)
        conv = (fmaxf(fmaxf(wred[0], wred[1]), fmaxf(wred[2], wred[3])) < 3e-5f) ? 1 : 0;
      __syncthreads();
      if (conv) { tcv = t; break; }
    }
  }
  if (tid == 0) ((int*)ws)[WS_TC] = tcv;

  // ---- epilogue: pair matrices M^2, MG, HM, HG of converged system ----
  {
    const float* Mf = ws + (size_t)tcv * MG_STRIDE;
    const float* Gf = Mf + SD*SD;
    unsigned* Mtp = Zbu;                       // M^T packed (alias, Aug dead)
    for (int s = tid; s < SD*SD; s += 256) {
      int i = s >> 6, j = s & 63;
      unsigned pk = packhl(Mf[s]);
      Pb[i*68 + j] = pk;                       // M row-major (Pb dead)
      Mtp[j*68 + i] = pk;
    }
    for (int s = tid; s < SD*NV; s += 256) {
      int i = s >> 5, v = s & 31;
      Ktb[v*68 + i] = packhl(Gf[s]);           // G^T row-major (Ktb dead)
    }
    __syncthreads();
    float* M2o = ws + WS_PAIR;
    float* MGo = M2o + 4096;
    float* HMo = MGo + 2048;
    float* HGo = HMo + 2048;
    for (int tt = w; tt < 36; tt += 4) {
      if (tt < 16) {                           // M2 = M @ M
        const int m0 = (tt >> 2) << 4, n0 = (tt & 3) << 4;
        f32x4 c = {0.f, 0.f, 0.f, 0.f};
        c = mfma3(Pb + (m0+l16)*68 +      quad*8, Mtp + (n0+l16)*68 +      quad*8, c);
        c = mfma3(Pb + (m0+l16)*68 + 32 + quad*8, Mtp + (n0+l16)*68 + 32 + quad*8, c);
        const int r0 = m0 + quad*4, cc = n0 + l16;
#pragma unroll
        for (int g = 0; g < 4; ++g) M2o[(r0+g)*SD + cc] = c[g];
      } else if (tt < 24) {                    // MG = M @ G
        const int ss = tt - 16;
        const int m0 = (ss >> 1) << 4, n0 = (ss & 1) << 4;
        f32x4 c = {0.f, 0.f, 0.f, 0.f};
        c = mfma3(Pb + (m0+l16)*68 +      quad*8, Ktb + (n0+l16)*68 +      quad*8, c);
        c = mfma3(Pb + (m0+l16)*68 + 32 + quad*8, Ktb + (n0+l16)*68 + 32 + quad*8, c);
        const int r0 = m0 + quad*4, cc = n0 + l16;
#pragma unroll
        for (int g = 0; g < 4; ++g) MGo[(r0+g)*NV + cc] = c[g];
      } else if (tt < 32) {                    // HM = H @ M
        const int ss = tt - 24;
        const int m0 = (ss >> 2) << 4, n0 = (ss & 3) << 4;
        f32x4 c = {0.f, 0.f, 0.f, 0.f};
        c = mfma3(Hb + (m0+l16)*68 +      quad*8, Mtp + (n0+l16)*68 +      quad*8, c);
        c = mfma3(Hb + (m0+l16)*68 + 32 + quad*8, Mtp + (n0+l16)*68 + 32 + quad*8, c);
        const int r0 = m0 + quad*4, cc = n0 + l16;
#pragma unroll
        for (int g = 0; g < 4; ++g) HMo[(r0+g)*SD + cc] = c[g];
      } else {                                 // HG = H @ G
        const int ss = tt - 32;
        const int m0 = (ss >> 1) << 4, n0 = (ss & 1) << 4;
        f32x4 c = {0.f, 0.f, 0.f, 0.f};
        c = mfma3(Hb + (m0+l16)*68 +      quad*8, Ktb + (n0+l16)*68 +      quad*8, c);
        c = mfma3(Hb + (m0+l16)*68 + 32 + quad*8, Ktb + (n0+l16)*68 + 32 + quad*8, c);
        const int r0 = m0 + quad*4, cc = n0 + l16;
#pragma unroll
        for (int g = 0; g < 4; ++g) HGo[(r0+g)*NV + cc] = c[g];
      }
    }
  }
}

__launch_bounds__(256)
__global__ void kf_phase2(const float* __restrict__ x,
                          const float* __restrict__ Hg,
                          const float* __restrict__ ws,
                          float* __restrict__ out) {
  __shared__ __align__(16) float Hs2[NV*65];
  __shared__ __align__(16) float xt[TSZ*36];
  __shared__ __align__(16) float yb[NV*129];
  __shared__ __align__(16) float mbuf[2*SD];
  __shared__ __align__(16) float M2s[SD*68];
  __shared__ __align__(16) float MGs[SD*36];
  __shared__ __align__(16) float Gs [SD*36];
  __shared__ __align__(16) float HMs[NV*68];
  __shared__ __align__(16) float HGs[NV*36];
  const int tid = threadIdx.x, b = blockIdx.x;

  const int tc = ((const int*)ws)[WS_TC];
  const float* M2o = ws + WS_PAIR;
  const float* MGo = M2o + 4096;
  const float* HMo = MGo + 2048;
  const float* HGo = HMo + 2048;
  const float* Gf  = ws + (size_t)tc * MG_STRIDE + SD*SD;

  for (int s = tid; s < NV*SD; s += 256) {
    Hs2[(s>>6)*65 + (s&63)] = Hg[s];
    HMs[(s>>6)*68 + (s&63)] = HMo[s];
  }
  for (int s = tid; s < SD*SD; s += 256) M2s[(s>>6)*68 + (s&63)] = M2o[s];
  for (int s = tid; s < SD*NV; s += 256) {
    MGs[(s>>5)*36 + (s&31)] = MGo[s];
    Gs [(s>>5)*36 + (s&31)] = Gf[s];
  }
  for (int s = tid; s < NV*NV; s += 256) HGs[(s>>5)*36 + (s&31)] = HGo[s];
  for (int s = tid; s < NV*TSZ; s += 256) {
    int v = s >> 7, t = s & 127;
    xt[t*36 + v] = x[(size_t)b*NV*TSZ + s];
  }
  if (tid < NV) yb[tid*129] = 0.0f;
  if (tid < 2*SD) mbuf[tid] = 0.0f;
  __syncthreads();

  const int i = tid >> 2, p4 = tid & 3;        // m rows: 4 threads per row
  const int v = tid >> 3, p8 = tid & 7;        // y rows: 8 threads per row

  // ---- transient: single steps t = 0..tc-1 (emit y_1..y_{tc-1}) ----
  for (int t = 0; t < tc; ++t) {
    const float* Mt = ws + (size_t)t * MG_STRIDE;
    const float* Gt = Mt + SD*SD;
    const float* cur = mbuf + (t & 1) * SD;
    float*       nxt = mbuf + ((t + 1) & 1) * SD;

    float acc = 0.0f;
    {
      const int j0 = p4 * 16;
#pragma unroll
      for (int c = 0; c < 16; c += 4) {
        float4 mm = *(const float4*)(Mt + i*SD + j0 + c);
        float4 vv = *(const float4*)(cur + j0 + c);
        acc += mm.x*vv.x + mm.y*vv.y + mm.z*vv.z + mm.w*vv.w;
      }
      const int v0 = p4 * 8;
#pragma unroll
      for (int c = 0; c < 8; c += 4) {
        float4 gg = *(const float4*)(Gt + i*NV + v0 + c);
        float4 oo = *(const float4*)(xt + t*36 + v0 + c);
        acc += gg.x*oo.x + gg.y*oo.y + gg.z*oo.z + gg.w*oo.w;
      }
    }
    acc += __shfl_xor(acc, 1);
    acc += __shfl_xor(acc, 2);

    if (t >= 1) {
      float ys = 0.0f;
#pragma unroll
      for (int j = 0; j < 8; ++j)
        ys += Hs2[v*65 + p8*8 + j] * cur[p8*8 + j];
      ys += __shfl_xor(ys, 1);
      ys += __shfl_xor(ys, 2);
      ys += __shfl_xor(ys, 4);
      if (p8 == 0) yb[v*129 + t] = ys;
    }
    if (p4 == 0) nxt[i] = acc;
    __syncthreads();
  }

  // ---- pair steps: y_t, y_{t+1}, m_{t+2} all from m_t; 1 barrier / 2 steps --
  int t = tc;
  int cb = tc & 1;
  for (; t + 1 < TSZ; t += 2) {
    const float* cur = mbuf + cb * SD;
    float*       nxt = mbuf + (cb ^ 1) * SD;

    // y_t = H m_t
    float ys = 0.0f;
#pragma unroll
    for (int j = 0; j < 8; ++j)
      ys += Hs2[v*65 + p8*8 + j] * cur[p8*8 + j];
    ys += __shfl_xor(ys, 1);
    ys += __shfl_xor(ys, 2);
    ys += __shfl_xor(ys, 4);
    if (p8 == 0) yb[v*129 + t] = ys;

    // y_{t+1} = HM m_t + HG o_t
    float yq = 0.0f;
#pragma unroll
    for (int c = 0; c < 8; c += 4) {
      float4 hm = *(const float4*)(HMs + v*68 + p8*8 + c);
      float4 vv = *(const float4*)(cur + p8*8 + c);
      yq += hm.x*vv.x + hm.y*vv.y + hm.z*vv.z + hm.w*vv.w;
    }
    {
      float4 hg = *(const float4*)(HGs + v*36 + p8*4);
      float4 oo = *(const float4*)(xt + t*36 + p8*4);
      yq += hg.x*oo.x + hg.y*oo.y + hg.z*oo.z + hg.w*oo.w;
    }
    yq += __shfl_xor(yq, 1);
    yq += __shfl_xor(yq, 2);
    yq += __shfl_xor(yq, 4);
    if (p8 == 0) yb[v*129 + t + 1] = yq;

    // m_{t+2} = M2 m_t + MG o_t + G o_{t+1}
    float acc = 0.0f;
    {
      const int j0 = p4 * 16;
#pragma unroll
      for (int c = 0; c < 16; c += 4) {
        float4 mm = *(const float4*)(M2s + i*68 + j0 + c);
        float4 vv = *(const float4*)(cur + j0 + c);
        acc += mm.x*vv.x + mm.y*vv.y + mm.z*vv.z + mm.w*vv.w;
      }
      const int v0 = p4 * 8;
#pragma unroll
      for (int c = 0; c < 8; c += 4) {
        float4 gg = *(const float4*)(MGs + i*36 + v0 + c);
        float4 oo = *(const float4*)(xt + t*36 + v0 + c);
        acc += gg.x*oo.x + gg.y*oo.y + gg.z*oo.z + gg.w*oo.w;
        float4 g2 = *(const float4*)(Gs + i*36 + v0 + c);
        float4 o2 = *(const float4*)(xt + (t+1)*36 + v0 + c);
        acc += g2.x*o2.x + g2.y*o2.y + g2.z*o2.z + g2.w*o2.w;
      }
    }
    acc += __shfl_xor(acc, 1);
    acc += __shfl_xor(acc, 2);
    if (p4 == 0) nxt[i] = acc;
    __syncthreads();
    cb ^= 1;
  }
  if (t == TSZ - 1) {                          // odd tail: y_127 = H m_127
    const float* cur = mbuf + cb * SD;
    float ys = 0.0f;
#pragma unroll
    for (int j = 0; j < 8; ++j)
      ys += Hs2[v*65 + p8*8 + j] * cur[p8*8 + j];
    ys += __shfl_xor(ys, 1);
    ys += __shfl_xor(ys, 2);
    ys += __shfl_xor(ys, 4);
    if (p8 == 0) yb[v*129 + t] = ys;
    __syncthreads();
  }

  for (int s = tid; s < NV*TSZ; s += 256)
    out[(size_t)b*NV*TSZ + s] = yb[(s>>7)*129 + (s&127)];
}

extern "C" void kernel_launch(void* const* d_in, const int* in_sizes, int n_in,
                              void* d_out, int out_size, void* d_ws, size_t ws_size,
                              hipStream_t stream) {
  const float* x = (const float*)d_in[0];
  const float* F = (const float*)d_in[1];
  const float* H = (const float*)d_in[2];
  const float* R = (const float*)d_in[3];
  const float* Q = (const float*)d_in[4];
  float* out = (float*)d_out;
  float* ws  = (float*)d_ws;   // 127*6144*4 B ~= 3.12 MB (same footprint as R1)

  hipLaunchKernelGGL(kf_phase1, dim3(1), dim3(256), 0, stream, F, H, R, Q, ws);
  hipLaunchKernelGGL(kf_phase2, dim3(BSZ), dim3(256), 0, stream, x, H, ws, out);
}